// Round 6
// baseline (340.748 us; speedup 1.0000x reference)
//
#include <hip/hip_runtime.h>
#include <stdint.h>

#define DEVI __device__ __forceinline__
#define LOG2E 1.4426950408889634f

typedef short bf16x8 __attribute__((ext_vector_type(8)));
typedef float f32x4 __attribute__((ext_vector_type(4)));

// analytically-derived max of the gamma positional basis (i=0, ap=36):
// exp(3*ln36 - 3 - ln6 - 4*ln12) = 0.01867013 (input-independent constant)
#define PMAX 0.01867013f

DEVI float b2f(unsigned short u) {
  union { unsigned u32; float f; } x;
  x.u32 = ((unsigned)u) << 16;
  return x.f;
}
DEVI unsigned short f2b(float f) {
  union { float f32; unsigned u32; } x;
  x.f32 = f;
  unsigned u = x.u32;
  return (unsigned short)((u + 0x7FFFu + ((u >> 16) & 1u)) >> 16);
}

// async global->LDS, 16B per lane. LDS dest must be wave-uniform base + lane*16.
DEVI void gload16(const unsigned short* g, unsigned short* l) {
  __builtin_amdgcn_global_load_lds(
      (const __attribute__((address_space(1))) void*)g,
      (__attribute__((address_space(3))) void*)l, 16, 0, 0);
}

DEVI float gamma_prob(float ap, int i) {
  float mean = 48.f * (float)(i + 1);
  float conc = (mean / 24.f) * (mean / 24.f);
  float rate = mean / 576.f;
  if (ap == 0.f) return 1e-8f;
  float logp = (conc - 1.f) * logf(ap) - rate * ap - (lgammaf(conc) - conc * logf(rate));
  return expf(logp) + 1e-8f;
}

// ---------------------------------------------------- device transpose (32x32)
DEVI void dev_transpose(const float* srcf, const unsigned short* srcb, int src_ld,
                        unsigned short* dst, int dst_ld, int rows, int cols,
                        int bx, int by, unsigned short (*t)[33]) {
  int tx = threadIdx.x & 31, ty = threadIdx.x >> 5;
  int r0 = by * 32, c0 = bx * 32;
#pragma unroll
  for (int i = 0; i < 4; i++) {
    int r = r0 + ty + i * 8, cc = c0 + tx;
    if (r < rows && cc < cols)
      t[ty + i * 8][tx] = srcf ? f2b(srcf[(size_t)r * src_ld + cc])
                               : srcb[(size_t)r * src_ld + cc];
  }
  __syncthreads();
#pragma unroll
  for (int i = 0; i < 4; i++) {
    int dr = c0 + ty + i * 8, dc = r0 + tx;
    if (dr < cols && dc < rows) dst[(size_t)dr * dst_ld + dc] = t[tx][ty + i * 8];
  }
}

// ------------------------------------------------------------------ k_prep
__global__ __launch_bounds__(256) void k_prep(
    const float* __restrict__ x, const float* __restrict__ Wq,
    const float* __restrict__ Wk, const float* __restrict__ Wv,
    const float* __restrict__ Wemb, const float* __restrict__ Wrk,
    unsigned short* __restrict__ xb, unsigned short* __restrict__ WqkvT,
    unsigned short* __restrict__ WembT, unsigned short* __restrict__ WrkT,
    unsigned short* __restrict__ emb) {
  __shared__ unsigned short t[32][33];
  int bid = blockIdx.x;
  if (bid < 4608) {
    int i = (bid * 256 + threadIdx.x) * 4;
    float4 v = *(const float4*)(x + i);
    ushort4 o;
    o.x = f2b(v.x); o.y = f2b(v.y); o.z = f2b(v.z); o.w = f2b(v.w);
    *(ushort4*)(xb + i) = o;
  } else if (bid < 5376) {
    int s = bid - 4608;
    dev_transpose(Wq, nullptr, 512, WqkvT, 1536, 1536, 512, s % 16, s / 16, t);
  } else if (bid < 6144) {
    int s = bid - 5376;
    dev_transpose(Wk, nullptr, 512, WqkvT + (size_t)512 * 1536, 1536, 1536, 512, s % 16, s / 16, t);
  } else if (bid < 8448) {
    int s = bid - 6144;
    dev_transpose(Wv, nullptr, 1536, WqkvT + (size_t)1024 * 1536, 1536, 1536, 1536, s % 48, s / 48, t);
  } else if (bid < 10752) {
    int s = bid - 8448;
    dev_transpose(Wemb, nullptr, 1536, WembT, 1536, 1536, 1536, s % 48, s / 48, t);
  } else if (bid < 10848) {
    int s = bid - 10752;
    dev_transpose(Wrk, nullptr, 512, WrkT, 192, 192, 512, s % 16, s / 16, t);
  } else {
    int idx = (bid - 10848) * 256 + threadIdx.x;
    if (idx < 3071 * 96) {
      int m = idx / 96, cc = idx % 96;
      float ap = fabsf((float)(m - 1535));
      float val;
      if (cc < 32) {
        float max_range = logf(1536.f) * 1.4426950408889634f;
        float l = 3.f + (float)cc * (max_range - 3.f) / 31.f;
        val = exp2f(-ap * exp2f(-l));
      } else if (cc < 64) {
        float width = exp2f((float)(cc - 31)) - 1.f;
        val = (width > ap) ? 1.f : 0.f;
      } else {
        val = gamma_prob(ap, cc - 64) / PMAX;
      }
      float sgn = (m > 1535) ? 1.f : ((m < 1535) ? -1.f : 0.f);
      emb[(size_t)m * 192 + cc] = f2b(val);
      emb[(size_t)m * 192 + 96 + cc] = f2b(sgn * val);
    }
  }
}

// ---------------------------------------------------------------- MFMA GEMM
DEVI void dev_gemm(const unsigned short* __restrict__ A, const unsigned short* __restrict__ Bt,
                   unsigned short* Cb, float* Cf, int M, int N, int K,
                   int bx, int by, unsigned short* As, unsigned short* Bs) {
  int tid = threadIdx.x;
  int w = tid >> 6, L = tid & 63, g = L >> 4, c = L & 15;
  int m0 = by << 7, n0 = bx << 7;
  int wm = (w >> 1) << 6, wn = (w & 1) << 6;
  f32x4 acc[4][4];
#pragma unroll
  for (int i = 0; i < 4; i++)
#pragma unroll
    for (int j = 0; j < 4; j++) acc[i][j] = (f32x4){0.f, 0.f, 0.f, 0.f};
  int nkt = K >> 5;
  for (int kt = 0; kt < nkt; kt++) {
    int k0 = kt << 5;
#pragma unroll
    for (int i2 = 0; i2 < 2; i2++) {
      int cidx = tid + (i2 << 8);
      int row = cidx >> 2, kc = (cidx & 3) << 3;
      int ra = m0 + row;
      if (ra >= M) ra = M - 1;
      gload16(A + (size_t)ra * K + k0 + kc, As + cidx * 8);
      gload16(Bt + (size_t)(n0 + row) * K + k0 + kc, Bs + cidx * 8);
    }
    __syncthreads();
    bf16x8 af[4], bfr[4];
#pragma unroll
    for (int t = 0; t < 4; t++) af[t] = *(const bf16x8*)(As + (wm + t * 16 + c) * 32 + g * 8);
#pragma unroll
    for (int t = 0; t < 4; t++) bfr[t] = *(const bf16x8*)(Bs + (wn + t * 16 + c) * 32 + g * 8);
#pragma unroll
    for (int mt = 0; mt < 4; mt++)
#pragma unroll
      for (int nt = 0; nt < 4; nt++)
        acc[mt][nt] = __builtin_amdgcn_mfma_f32_16x16x32_bf16(af[mt], bfr[nt], acc[mt][nt], 0, 0, 0);
    __syncthreads();
  }
#pragma unroll
  for (int mt = 0; mt < 4; mt++)
#pragma unroll
    for (int nt = 0; nt < 4; nt++)
#pragma unroll
      for (int r = 0; r < 4; r++) {
        int rr = m0 + wm + mt * 16 + g * 4 + r;
        if (rr < M) {
          size_t o = (size_t)rr * N + n0 + wn + nt * 16 + c;
          if (Cf) Cf[o] = acc[mt][nt][r];
          else Cb[o] = f2b(acc[mt][nt][r]);
        }
      }
}

__global__ __launch_bounds__(256) void k_gemm(
    const unsigned short* __restrict__ A, const unsigned short* __restrict__ Bt,
    unsigned short* Cb, float* Cf, int M, int N, int K) {
  __shared__ unsigned short sm[8192];
  dev_gemm(A, Bt, Cb, Cf, M, N, K, blockIdx.x, blockIdx.y, sm, sm + 4096);
}

// ------------------------------------------------------------------ k_mid
__global__ __launch_bounds__(256) void k_mid(
    const unsigned short* __restrict__ emb, const unsigned short* __restrict__ WrkT,
    unsigned short* __restrict__ rkb, const unsigned short* __restrict__ QKV,
    unsigned short* __restrict__ Vt) {
  __shared__ unsigned short sm[8192];
  int bid = blockIdx.x;
  if (bid < 96) {
    dev_gemm(emb, WrkT, rkb, nullptr, 3071, 512, 192, bid & 3, bid >> 2, sm, sm + 4096);
  } else {
    int tt = bid - 96;
    int which = tt / 2304;
    tt %= 2304;
    dev_transpose(nullptr, QKV + 1024 + (size_t)which * 1536 * 2560, 2560,
                  Vt + (size_t)which * 1536 * 1536, 1536, 1536, 1536,
                  tt % 48, tt / 48, (unsigned short (*)[33])sm);
  }
}

// ------------------------------------------------------------ flash attention
// r6: BALANCED RESIDENCY. r5 confirmed the flash structure (70us, 0 bank
// conflicts) but grid 384 @ 2 blocks/CU = half the CUs run 2 blocks (24
// jt-units) while half run 1 then idle -> ~33% imbalance tax + only 4-8
// waves/CU. Fix: key-split 2->4 (6 jt per block, grid 768) + single-buffered
// K (stage K(jt+1) AFTER the MID barrier -- all content reads done; drains at
// the END barrier) -> LDS 48KB -> 3 blocks/CU -> 768 = exactly 3x256, every
// CU identical, 12 waves/CU. O-partials stored bf16 (4-way merge at f32 would
// double k_fin traffic; quantization error is same order as the existing
// Obuf bf16 step; FALLBACK if absmax fails: f32 partials, +13us).
// exp2 trick: LOG2E folded into Q fragments -> p = exp2f(lg), no per-elem mul.
// Barrier/race audit per jt: V(jt) issued at top, drained at MID; K(jt+1)
// issued after MID (content reads of K(jt) complete), drained at END; PV
// ds_reads of V/P complete at END before next stageV/P-write.
__global__ __launch_bounds__(256, 3) void k_attn(
    const unsigned short* __restrict__ QKV, const unsigned short* __restrict__ rk,
    const unsigned short* __restrict__ Vt, const float* __restrict__ rwb,
    const float* __restrict__ rrb, unsigned short* __restrict__ Opart,
    float* __restrict__ lpart) {
  // u16 layout: K [0,4096); V [4096,16384); P slabs [16384,24576)  (48 KB)
  __shared__ unsigned short lds[24576];
  const int tid = threadIdx.x;
  const int w = tid >> 6, L = tid & 63, g = L >> 4, c = L & 15;
  const int bid = blockIdx.x;
  const int h = bid & 7, b = (bid >> 3) & 1, kh = (bid >> 4) & 3;
  const int i0b = (bid >> 6) << 7;   // 128-row q-block base (12 q-blocks)
  const int qp = i0b + w * 32;       // this wave's 32-row q-pair base
  const int bh = b * 8 + h;
  const int c7s = (c & 7) << 3;      // u16-index swizzle term for reads

  // staging lane decode (shared by K and V stages)
  const int lrow8 = L >> 3;                                // 0..7
  const int lbo = (((L & 7) * 16) ^ ((lrow8 & 7) << 4));   // swizzled byte in 128B row

  // Q fragments for both q-subtiles: [qi][ks]; content uses rwb, rel uses rrb.
  // LOG2E folded in so softmax uses exp2f directly.
  bf16x8 aqw[2][2], aqr[2][2];
#pragma unroll
  for (int qi = 0; qi < 2; qi++) {
    const unsigned short* qrow =
        QKV + (size_t)(b * 1536 + qp + qi * 16 + c) * 2560 + h * 64;
#pragma unroll
    for (int ks = 0; ks < 2; ks++) {
      union { bf16x8 v; unsigned short s[8]; } uw, ur;
#pragma unroll
      for (int j = 0; j < 8; j++) {
        int d = ks * 32 + g * 8 + j;
        float qv = b2f(qrow[d]) * 0.125f;
        uw.s[j] = f2b((qv + rwb[h * 64 + d]) * LOG2E);
        ur.s[j] = f2b((qv + rrb[h * 64 + d]) * LOG2E);
      }
      aqw[qi][ks] = uw.v;
      aqr[qi][ks] = ur.v;
    }
  }

  // bpermute addresses / selects for the folded relative shift
  int baddr[4], bsel[4];
#pragma unroll
  for (int r = 0; r < 4; r++) {
    int u = c - (g * 4 + r) + 15;  // in [0,30]
    baddr[r] = (((g << 4) | (u & 15)) << 2);
    bsel[r] = (u >> 4) & 1;
  }

  f32x4 Ofr[8][3];  // [q-slab][v-tile of this wave's 48 vdims]
#pragma unroll
  for (int s = 0; s < 8; s++)
#pragma unroll
    for (int t = 0; t < 3; t++) Ofr[s][t] = (f32x4){0.f, 0.f, 0.f, 0.f};
  float lrow[2][4] = {{0.f, 0.f, 0.f, 0.f}, {0.f, 0.f, 0.f, 0.f}};

  const unsigned short* rkh = rk + h * 64;
  const size_t kgbase = (size_t)(b * 1536 + kh * 384) * 2560 + 512 + h * 64;
  const size_t vgbase = (size_t)(bh * 192) * 1536 + kh * 384;

  // ---- staging helpers (wave w covers its share; dest wave-uniform) ----
  auto stageK = [&](int kt) {
#pragma unroll
    for (int i = 0; i < 2; i++) {
      int key = w * 16 + i * 8 + lrow8;
      const unsigned short* src =
          QKV + kgbase + (size_t)(kt * 64 + key) * 2560 + (lbo >> 1);
      gload16(src, lds + w * 1024 + i * 512);
    }
  };
  auto stageV = [&](int kt) {
#pragma unroll
    for (int i = 0; i < 6; i++) {
      int vd = w * 48 + i * 8 + lrow8;
      const unsigned short* src =
          Vt + vgbase + (size_t)vd * 1536 + kt * 64 + (lbo >> 1);
      gload16(src, lds + 4096 + w * 3072 + i * 512);
    }
  };

  stageK(0);
  __syncthreads();

  for (int jt = 0; jt < 6; jt++) {
    // issue V(jt) DMA; drains at the MID barrier
    stageV(jt);

    const int j0g = kh * 384 + jt * 64;
    const int moff1 = j0g - (qp + 16) + 1520;  // rel-window base for qi=1

    // ---- content scores: each K fragment (from LDS) feeds BOTH q-tiles
    f32x4 Sc[2][4];
#pragma unroll
    for (int nt = 0; nt < 4; nt++) {
      const int kro = (nt * 16 + c) * 64;
      bf16x8 kf0 = *(const bf16x8*)(lds + kro + ((g * 8) ^ c7s));
      bf16x8 kf1 = *(const bf16x8*)(lds + kro + ((32 + g * 8) ^ c7s));
      f32x4 z0 = (f32x4){0.f, 0.f, 0.f, 0.f};
      z0 = __builtin_amdgcn_mfma_f32_16x16x32_bf16(aqw[0][0], kf0, z0, 0, 0, 0);
      z0 = __builtin_amdgcn_mfma_f32_16x16x32_bf16(aqw[0][1], kf1, z0, 0, 0, 0);
      Sc[0][nt] = z0;
      f32x4 z1 = (f32x4){0.f, 0.f, 0.f, 0.f};
      z1 = __builtin_amdgcn_mfma_f32_16x16x32_bf16(aqw[1][0], kf0, z1, 0, 0, 0);
      z1 = __builtin_amdgcn_mfma_f32_16x16x32_bf16(aqw[1][1], kf1, z1, 0, 0, 0);
      Sc[1][nt] = z1;
    }

    // ---- rel band: union pass over 6 rk tiles serves both windows (r4 code)
    float bandp0[4], bandp1[4];
    {  // j = 0: qi=1 initial only
      int mg = moff1 + c;
      const unsigned short* rrow = rkh + (size_t)mg * 512;
      f32x4 z = (f32x4){0.f, 0.f, 0.f, 0.f};
      z = __builtin_amdgcn_mfma_f32_16x16x32_bf16(aqr[1][0], *(const bf16x8*)(rrow + g * 8), z, 0, 0, 0);
      z = __builtin_amdgcn_mfma_f32_16x16x32_bf16(aqr[1][1], *(const bf16x8*)(rrow + 32 + g * 8), z, 0, 0, 0);
#pragma unroll
      for (int r = 0; r < 4; r++)
        bandp1[r] = __int_as_float(__builtin_amdgcn_ds_bpermute(baddr[r], __float_as_int(z[r])));
    }
#pragma unroll
    for (int j = 1; j <= 5; j++) {
      int mg = moff1 + 16 * j + c;
      if (mg > 3070) mg = 3070;  // clamped lane feeds only unused band slots
      const unsigned short* rrow = rkh + (size_t)mg * 512;
      bf16x8 rf0 = *(const bf16x8*)(rrow + g * 8);
      bf16x8 rf1 = *(const bf16x8*)(rrow + 32 + g * 8);
      {  // qi=0 uses this tile as window index j-1
        f32x4 z = (f32x4){0.f, 0.f, 0.f, 0.f};
        z = __builtin_amdgcn_mfma_f32_16x16x32_bf16(aqr[0][0], rf0, z, 0, 0, 0);
        z = __builtin_amdgcn_mfma_f32_16x16x32_bf16(aqr[0][1], rf1, z, 0, 0, 0);
        if (j == 1) {
#pragma unroll
          for (int r = 0; r < 4; r++)
            bandp0[r] = __int_as_float(__builtin_amdgcn_ds_bpermute(baddr[r], __float_as_int(z[r])));
        } else {
          const int nt = j - 2;
#pragma unroll
          for (int r = 0; r < 4; r++) {
            float bandc = __int_as_float(__builtin_amdgcn_ds_bpermute(baddr[r], __float_as_int(z[r])));
            Sc[0][nt][r] += bsel[r] ? bandc : bandp0[r];
            bandp0[r] = bandc;
          }
        }
      }
      if (j <= 4) {  // qi=1 uses this tile as window index j
        f32x4 z = (f32x4){0.f, 0.f, 0.f, 0.f};
        z = __builtin_amdgcn_mfma_f32_16x16x32_bf16(aqr[1][0], rf0, z, 0, 0, 0);
        z = __builtin_amdgcn_mfma_f32_16x16x32_bf16(aqr[1][1], rf1, z, 0, 0, 0);
        const int nt = j - 1;
#pragma unroll
        for (int r = 0; r < 4; r++) {
          float bandc = __int_as_float(__builtin_amdgcn_ds_bpermute(baddr[r], __float_as_int(z[r])));
          Sc[1][nt][r] += bsel[r] ? bandc : bandp1[r];
          bandp1[r] = bandc;
        }
      }
    }

    // ---- p = exp2(lg) (LOG2E pre-folded); partial sums; P -> swizzled slabs
#pragma unroll
    for (int qi = 0; qi < 2; qi++) {
      unsigned short* slab = lds + 16384 + (2 * w + qi) * 1024;
#pragma unroll
      for (int nt = 0; nt < 4; nt++)
#pragma unroll
        for (int r = 0; r < 4; r++) {
          float p = exp2f(Sc[qi][nt][r]);
          lrow[qi][r] += p;
          int q = g * 4 + r;
          slab[q * 64 + ((nt * 16 + c) ^ ((q & 7) << 3))] = f2b(p);
        }
    }

    __syncthreads();  // MID: P visible to all waves; V(jt) DMA drained

    // issue K(jt+1) DMA into the (now free) single K buffer; drains at END
    if (jt < 5) stageK(jt + 1);

    // ---- PV: staged V tile serves ALL 8 q-slabs (this wave's 48 vdims)
    bf16x8 vf0[3], vf1[3];
#pragma unroll
    for (int vt = 0; vt < 3; vt++) {
      const int vro = 4096 + (w * 48 + vt * 16 + c) * 64;
      vf0[vt] = *(const bf16x8*)(lds + vro + ((g * 8) ^ c7s));
      vf1[vt] = *(const bf16x8*)(lds + vro + ((32 + g * 8) ^ c7s));
    }
    __builtin_amdgcn_s_setprio(1);
#pragma unroll
    for (int s = 0; s < 8; s++) {
      const unsigned short* slab = lds + 16384 + s * 1024;
      bf16x8 ap0 = *(const bf16x8*)(slab + c * 64 + ((g * 8) ^ c7s));
      bf16x8 ap1 = *(const bf16x8*)(slab + c * 64 + ((32 + g * 8) ^ c7s));
#pragma unroll
      for (int vt = 0; vt < 3; vt++) {
        Ofr[s][vt] = __builtin_amdgcn_mfma_f32_16x16x32_bf16(ap0, vf0[vt], Ofr[s][vt], 0, 0, 0);
        Ofr[s][vt] = __builtin_amdgcn_mfma_f32_16x16x32_bf16(ap1, vf1[vt], Ofr[s][vt], 0, 0, 0);
      }
    }
    __builtin_amdgcn_s_setprio(0);

    __syncthreads();  // END: PV ds_reads done; K(jt+1) DMA drained
  }

  // ---- l partials: reduce lrow over the 16 c-lanes, write global (no merge)
#pragma unroll
  for (int qi = 0; qi < 2; qi++)
#pragma unroll
    for (int r = 0; r < 4; r++) {
      float s = lrow[qi][r];
      s += __shfl_xor(s, 1, 64);
      s += __shfl_xor(s, 2, 64);
      s += __shfl_xor(s, 4, 64);
      s += __shfl_xor(s, 8, 64);
      lrow[qi][r] = s;
    }
  if (c == 0) {
#pragma unroll
    for (int qi = 0; qi < 2; qi++)
#pragma unroll
      for (int r = 0; r < 4; r++)
        lpart[(size_t)((kh * 2 + b) * 8 + h) * 1536 + qp + qi * 16 + g * 4 + r] =
            lrow[qi][r];
  }
  // ---- O partials (unnormalized, bf16); waves own disjoint vdim ranges
#pragma unroll
  for (int s = 0; s < 8; s++)
#pragma unroll
    for (int vt = 0; vt < 3; vt++)
#pragma unroll
      for (int r = 0; r < 4; r++)
        Opart[(size_t)(kh * 3072 + b * 1536 + i0b + s * 16 + g * 4 + r) * 1536 +
              h * 192 + w * 48 + vt * 16 + c] = f2b(Ofr[s][vt][r]);
}

// ------------------------------------------------------- key-split finalize
// out_bf16[row][col] = (sum of 4 bf16 partials) / (sum of 4 l's); 8 cols/thr.
__global__ __launch_bounds__(256) void k_fin(
    const unsigned short* __restrict__ Op, const float* __restrict__ lp,
    unsigned short* __restrict__ O) {
  int idx = (blockIdx.x * 256 + threadIdx.x) * 8;
  int row = idx / 1536, c0 = idx % 1536;  // row in [0,3072)
  int b = row >= 1536;
  int q = row - b * 1536, hh = c0 / 192;
  float l = 0.f;
#pragma unroll
  for (int kh = 0; kh < 4; kh++)
    l += lp[(size_t)((kh * 2 + b) * 8 + hh) * 1536 + q];
  float sc = 1.f / l;
  float acc[8] = {0.f, 0.f, 0.f, 0.f, 0.f, 0.f, 0.f, 0.f};
#pragma unroll
  for (int kh = 0; kh < 4; kh++) {
    const ushort4* p = (const ushort4*)(Op + (size_t)(kh * 3072 + row) * 1536 + c0);
#pragma unroll
    for (int half = 0; half < 2; half++) {
      ushort4 a = p[half];
      acc[half * 4 + 0] += b2f(a.x);
      acc[half * 4 + 1] += b2f(a.y);
      acc[half * 4 + 2] += b2f(a.z);
      acc[half * 4 + 3] += b2f(a.w);
    }
  }
#pragma unroll
  for (int half = 0; half < 2; half++) {
    ushort4 o;
    o.x = f2b(acc[half * 4 + 0] * sc);
    o.y = f2b(acc[half * 4 + 1] * sc);
    o.z = f2b(acc[half * 4 + 2] * sc);
    o.w = f2b(acc[half * 4 + 3] * sc);
    *(ushort4*)(O + (size_t)row * 1536 + c0 + half * 4) = o;
  }
}

// ------------------------------------------------------------------ launcher
extern "C" void kernel_launch(void* const* d_in, const int* in_sizes, int n_in,
                              void* d_out, int out_size, void* d_ws, size_t ws_size,
                              hipStream_t stream) {
  const float* x    = (const float*)d_in[0];
  const float* Wq   = (const float*)d_in[1];
  const float* Wk   = (const float*)d_in[2];
  const float* Wv   = (const float*)d_in[3];
  const float* Wrk  = (const float*)d_in[4];
  const float* Wemb = (const float*)d_in[5];
  const float* rwb  = (const float*)d_in[6];
  const float* rrb  = (const float*)d_in[7];

  char* ws = (char*)d_ws;
  size_t off = 0;
  auto alloc = [&](size_t bytes) -> void* {
    void* p = ws + off;
    off += (bytes + 255) & ~(size_t)255;
    return p;
  };
  unsigned short* xb    = (unsigned short*)alloc((size_t)3072 * 1536 * 2);
  unsigned short* WqkvT = (unsigned short*)alloc((size_t)2560 * 1536 * 2);
  unsigned short* WembT = (unsigned short*)alloc((size_t)1536 * 1536 * 2);
  unsigned short* WrkT  = (unsigned short*)alloc((size_t)512 * 192 * 2);
  unsigned short* QKV   = (unsigned short*)alloc((size_t)3072 * 2560 * 2);
  unsigned short* Vt    = (unsigned short*)alloc((size_t)2 * 1536 * 1536 * 2);
  unsigned short* emb   = (unsigned short*)alloc((size_t)3072 * 192 * 2);
  unsigned short* rkb   = (unsigned short*)alloc((size_t)3072 * 512 * 2);
  unsigned short* Obuf  = (unsigned short*)alloc((size_t)3072 * 1536 * 2);
  unsigned short* Opart = (unsigned short*)alloc((size_t)4 * 3072 * 1536 * 2);
  float*          lpart = (float*)alloc((size_t)4 * 2 * 8 * 1536 * 4);

  // 1) fused prep: x->bf16, 5 weight transposes, positional emb (pmax const)
  k_prep<<<12000, 256, 0, stream>>>(x, Wq, Wk, Wv, Wemb, Wrk, xb, WqkvT, WembT, WrkT, emb);
  // 2) fused QKV projection
  k_gemm<<<dim3(20, 24), 256, 0, stream>>>(xb, WqkvT, QKV, nullptr, 3072, 2560, 1536);
  // 3) rel-key GEMM + V transposes
  k_mid<<<4704, 256, 0, stream>>>(emb, WrkT, rkb, QKV, Vt);
  // 4) flash attention (QBLK=128, key-split=4, 48KB LDS, 3 blocks/CU exact)
  k_attn<<<768, 256, 0, stream>>>(QKV, rkb, Vt, rwb, rrb, Opart, lpart);
  // 5) merge key-split partials -> Obuf bf16
  k_fin<<<2304, 256, 0, stream>>>(Opart, lpart, Obuf);
  // 6) output projection -> f32 d_out
  k_gemm<<<dim3(12, 24), 256, 0, stream>>>(Obuf, WembT, nullptr, (float*)d_out, 3072, 1536, 1536);
}

// Round 7
// 278.794 us; speedup vs baseline: 1.2222x; 1.2222x over previous
//
#include <hip/hip_runtime.h>
#include <stdint.h>

#define DEVI __device__ __forceinline__
#define LOG2E 1.4426950408889634f

typedef short bf16x8 __attribute__((ext_vector_type(8)));
typedef float f32x4 __attribute__((ext_vector_type(4)));

// analytically-derived max of the gamma positional basis (i=0, ap=36):
// exp(3*ln36 - 3 - ln6 - 4*ln12) = 0.01867013 (input-independent constant)
#define PMAX 0.01867013f

DEVI float b2f(unsigned short u) {
  union { unsigned u32; float f; } x;
  x.u32 = ((unsigned)u) << 16;
  return x.f;
}
DEVI unsigned short f2b(float f) {
  union { float f32; unsigned u32; } x;
  x.f32 = f;
  unsigned u = x.u32;
  return (unsigned short)((u + 0x7FFFu + ((u >> 16) & 1u)) >> 16);
}

// async global->LDS, 16B per lane. LDS dest must be wave-uniform base + lane*16.
DEVI void gload16(const unsigned short* g, unsigned short* l) {
  __builtin_amdgcn_global_load_lds(
      (const __attribute__((address_space(1))) void*)g,
      (__attribute__((address_space(3))) void*)l, 16, 0, 0);
}

DEVI float gamma_prob(float ap, int i) {
  float mean = 48.f * (float)(i + 1);
  float conc = (mean / 24.f) * (mean / 24.f);
  float rate = mean / 576.f;
  if (ap == 0.f) return 1e-8f;
  float logp = (conc - 1.f) * logf(ap) - rate * ap - (lgammaf(conc) - conc * logf(rate));
  return expf(logp) + 1e-8f;
}

// ---------------------------------------------------- device transpose (32x32)
DEVI void dev_transpose(const float* srcf, const unsigned short* srcb, int src_ld,
                        unsigned short* dst, int dst_ld, int rows, int cols,
                        int bx, int by, unsigned short (*t)[33]) {
  int tx = threadIdx.x & 31, ty = threadIdx.x >> 5;
  int r0 = by * 32, c0 = bx * 32;
#pragma unroll
  for (int i = 0; i < 4; i++) {
    int r = r0 + ty + i * 8, cc = c0 + tx;
    if (r < rows && cc < cols)
      t[ty + i * 8][tx] = srcf ? f2b(srcf[(size_t)r * src_ld + cc])
                               : srcb[(size_t)r * src_ld + cc];
  }
  __syncthreads();
#pragma unroll
  for (int i = 0; i < 4; i++) {
    int dr = c0 + ty + i * 8, dc = r0 + tx;
    if (dr < cols && dc < rows) dst[(size_t)dr * dst_ld + dc] = t[tx][ty + i * 8];
  }
}

// ------------------------------------------------------------------ k_prep
__global__ __launch_bounds__(256) void k_prep(
    const float* __restrict__ x, const float* __restrict__ Wq,
    const float* __restrict__ Wk, const float* __restrict__ Wv,
    const float* __restrict__ Wemb, const float* __restrict__ Wrk,
    unsigned short* __restrict__ xb, unsigned short* __restrict__ WqkvT,
    unsigned short* __restrict__ WembT, unsigned short* __restrict__ WrkT,
    unsigned short* __restrict__ emb) {
  __shared__ unsigned short t[32][33];
  int bid = blockIdx.x;
  if (bid < 4608) {
    int i = (bid * 256 + threadIdx.x) * 4;
    float4 v = *(const float4*)(x + i);
    ushort4 o;
    o.x = f2b(v.x); o.y = f2b(v.y); o.z = f2b(v.z); o.w = f2b(v.w);
    *(ushort4*)(xb + i) = o;
  } else if (bid < 5376) {
    int s = bid - 4608;
    dev_transpose(Wq, nullptr, 512, WqkvT, 1536, 1536, 512, s % 16, s / 16, t);
  } else if (bid < 6144) {
    int s = bid - 5376;
    dev_transpose(Wk, nullptr, 512, WqkvT + (size_t)512 * 1536, 1536, 1536, 512, s % 16, s / 16, t);
  } else if (bid < 8448) {
    int s = bid - 6144;
    dev_transpose(Wv, nullptr, 1536, WqkvT + (size_t)1024 * 1536, 1536, 1536, 1536, s % 48, s / 48, t);
  } else if (bid < 10752) {
    int s = bid - 8448;
    dev_transpose(Wemb, nullptr, 1536, WembT, 1536, 1536, 1536, s % 48, s / 48, t);
  } else if (bid < 10848) {
    int s = bid - 10752;
    dev_transpose(Wrk, nullptr, 512, WrkT, 192, 192, 512, s % 16, s / 16, t);
  } else {
    int idx = (bid - 10848) * 256 + threadIdx.x;
    if (idx < 3071 * 96) {
      int m = idx / 96, cc = idx % 96;
      float ap = fabsf((float)(m - 1535));
      float val;
      if (cc < 32) {
        float max_range = logf(1536.f) * 1.4426950408889634f;
        float l = 3.f + (float)cc * (max_range - 3.f) / 31.f;
        val = exp2f(-ap * exp2f(-l));
      } else if (cc < 64) {
        float width = exp2f((float)(cc - 31)) - 1.f;
        val = (width > ap) ? 1.f : 0.f;
      } else {
        val = gamma_prob(ap, cc - 64) / PMAX;
      }
      float sgn = (m > 1535) ? 1.f : ((m < 1535) ? -1.f : 0.f);
      emb[(size_t)m * 192 + cc] = f2b(val);
      emb[(size_t)m * 192 + 96 + cc] = f2b(sgn * val);
    }
  }
}

// ---------------------------------------------------------------- MFMA GEMM
DEVI void dev_gemm(const unsigned short* __restrict__ A, const unsigned short* __restrict__ Bt,
                   unsigned short* Cb, float* Cf, int M, int N, int K,
                   int bx, int by, unsigned short* As, unsigned short* Bs) {
  int tid = threadIdx.x;
  int w = tid >> 6, L = tid & 63, g = L >> 4, c = L & 15;
  int m0 = by << 7, n0 = bx << 7;
  int wm = (w >> 1) << 6, wn = (w & 1) << 6;
  f32x4 acc[4][4];
#pragma unroll
  for (int i = 0; i < 4; i++)
#pragma unroll
    for (int j = 0; j < 4; j++) acc[i][j] = (f32x4){0.f, 0.f, 0.f, 0.f};
  int nkt = K >> 5;
  for (int kt = 0; kt < nkt; kt++) {
    int k0 = kt << 5;
#pragma unroll
    for (int i2 = 0; i2 < 2; i2++) {
      int cidx = tid + (i2 << 8);
      int row = cidx >> 2, kc = (cidx & 3) << 3;
      int ra = m0 + row;
      if (ra >= M) ra = M - 1;
      gload16(A + (size_t)ra * K + k0 + kc, As + cidx * 8);
      gload16(Bt + (size_t)(n0 + row) * K + k0 + kc, Bs + cidx * 8);
    }
    __syncthreads();
    bf16x8 af[4], bfr[4];
#pragma unroll
    for (int t = 0; t < 4; t++) af[t] = *(const bf16x8*)(As + (wm + t * 16 + c) * 32 + g * 8);
#pragma unroll
    for (int t = 0; t < 4; t++) bfr[t] = *(const bf16x8*)(Bs + (wn + t * 16 + c) * 32 + g * 8);
#pragma unroll
    for (int mt = 0; mt < 4; mt++)
#pragma unroll
      for (int nt = 0; nt < 4; nt++)
        acc[mt][nt] = __builtin_amdgcn_mfma_f32_16x16x32_bf16(af[mt], bfr[nt], acc[mt][nt], 0, 0, 0);
    __syncthreads();
  }
#pragma unroll
  for (int mt = 0; mt < 4; mt++)
#pragma unroll
    for (int nt = 0; nt < 4; nt++)
#pragma unroll
      for (int r = 0; r < 4; r++) {
        int rr = m0 + wm + mt * 16 + g * 4 + r;
        if (rr < M) {
          size_t o = (size_t)rr * N + n0 + wn + nt * 16 + c;
          if (Cf) Cf[o] = acc[mt][nt][r];
          else Cb[o] = f2b(acc[mt][nt][r]);
        }
      }
}

__global__ __launch_bounds__(256) void k_gemm(
    const unsigned short* __restrict__ A, const unsigned short* __restrict__ Bt,
    unsigned short* Cb, float* Cf, int M, int N, int K) {
  __shared__ unsigned short sm[8192];
  dev_gemm(A, Bt, Cb, Cf, M, N, K, blockIdx.x, blockIdx.y, sm, sm + 4096);
}

// ------------------------------------------------------------------ k_mid
__global__ __launch_bounds__(256) void k_mid(
    const unsigned short* __restrict__ emb, const unsigned short* __restrict__ WrkT,
    unsigned short* __restrict__ rkb, const unsigned short* __restrict__ QKV,
    unsigned short* __restrict__ Vt) {
  __shared__ unsigned short sm[8192];
  int bid = blockIdx.x;
  if (bid < 96) {
    dev_gemm(emb, WrkT, rkb, nullptr, 3071, 512, 192, bid & 3, bid >> 2, sm, sm + 4096);
  } else {
    int tt = bid - 96;
    int which = tt / 2304;
    tt %= 2304;
    dev_transpose(nullptr, QKV + 1024 + (size_t)which * 1536 * 2560, 2560,
                  Vt + (size_t)which * 1536 * 1536, 1536, 1536, 1536,
                  tt % 48, tt / 48, (unsigned short (*)[33])sm);
  }
}

// ------------------------------------------------------------ flash attention
// r7: r6 with the POISON REVERTED. r6's launch_bounds(256,3) squeezed the VGPR
// budget below the ~220 live values (Ofr[8][3] = 96 f32/lane) -> accumulator
// SPILL to scratch -> FETCH 9->193MB, WRITE 37->265MB, all scratch traffic
// (VGPR_Count 124->84 was the tell). Back to (256,2): VGPR budget 256, no
// spill. KEPT from r6 (all verified or benign): key-split 4 (6 jt/block, grid
// 768 -> ~3 blocks/CU sequential with backfill, skew <=1 block vs r5's 2-vs-1
// 50% imbalance); single-buffered K (stage K(jt+1) after MID barrier, drains
// at END); bf16 O-partials (absmax 6.1e-4 passed); exp2 with LOG2E pre-folded
// into Q. LDS 48KB: K [0,4096) V [4096,16384) P [16384,24576) u16.
// Barrier/race audit per jt: V(jt) issued at top, drained at MID; K(jt+1)
// issued after MID (content reads of K(jt) complete), drained at END; PV
// ds_reads of V/P complete at END before next stageV/P-write.
__global__ __launch_bounds__(256, 2) void k_attn(
    const unsigned short* __restrict__ QKV, const unsigned short* __restrict__ rk,
    const unsigned short* __restrict__ Vt, const float* __restrict__ rwb,
    const float* __restrict__ rrb, unsigned short* __restrict__ Opart,
    float* __restrict__ lpart) {
  // u16 layout: K [0,4096); V [4096,16384); P slabs [16384,24576)  (48 KB)
  __shared__ unsigned short lds[24576];
  const int tid = threadIdx.x;
  const int w = tid >> 6, L = tid & 63, g = L >> 4, c = L & 15;
  const int bid = blockIdx.x;
  const int h = bid & 7, b = (bid >> 3) & 1, kh = (bid >> 4) & 3;
  const int i0b = (bid >> 6) << 7;   // 128-row q-block base (12 q-blocks)
  const int qp = i0b + w * 32;       // this wave's 32-row q-pair base
  const int bh = b * 8 + h;
  const int c7s = (c & 7) << 3;      // u16-index swizzle term for reads

  // staging lane decode (shared by K and V stages)
  const int lrow8 = L >> 3;                                // 0..7
  const int lbo = (((L & 7) * 16) ^ ((lrow8 & 7) << 4));   // swizzled byte in 128B row

  // Q fragments for both q-subtiles: [qi][ks]; content uses rwb, rel uses rrb.
  // LOG2E folded in so softmax uses exp2f directly.
  bf16x8 aqw[2][2], aqr[2][2];
#pragma unroll
  for (int qi = 0; qi < 2; qi++) {
    const unsigned short* qrow =
        QKV + (size_t)(b * 1536 + qp + qi * 16 + c) * 2560 + h * 64;
#pragma unroll
    for (int ks = 0; ks < 2; ks++) {
      union { bf16x8 v; unsigned short s[8]; } uw, ur;
#pragma unroll
      for (int j = 0; j < 8; j++) {
        int d = ks * 32 + g * 8 + j;
        float qv = b2f(qrow[d]) * 0.125f;
        uw.s[j] = f2b((qv + rwb[h * 64 + d]) * LOG2E);
        ur.s[j] = f2b((qv + rrb[h * 64 + d]) * LOG2E);
      }
      aqw[qi][ks] = uw.v;
      aqr[qi][ks] = ur.v;
    }
  }

  // bpermute addresses / selects for the folded relative shift
  int baddr[4], bsel[4];
#pragma unroll
  for (int r = 0; r < 4; r++) {
    int u = c - (g * 4 + r) + 15;  // in [0,30]
    baddr[r] = (((g << 4) | (u & 15)) << 2);
    bsel[r] = (u >> 4) & 1;
  }

  f32x4 Ofr[8][3];  // [q-slab][v-tile of this wave's 48 vdims]
#pragma unroll
  for (int s = 0; s < 8; s++)
#pragma unroll
    for (int t = 0; t < 3; t++) Ofr[s][t] = (f32x4){0.f, 0.f, 0.f, 0.f};
  float lrow[2][4] = {{0.f, 0.f, 0.f, 0.f}, {0.f, 0.f, 0.f, 0.f}};

  const unsigned short* rkh = rk + h * 64;
  const size_t kgbase = (size_t)(b * 1536 + kh * 384) * 2560 + 512 + h * 64;
  const size_t vgbase = (size_t)(bh * 192) * 1536 + kh * 384;

  // ---- staging helpers (wave w covers its share; dest wave-uniform) ----
  auto stageK = [&](int kt) {
#pragma unroll
    for (int i = 0; i < 2; i++) {
      int key = w * 16 + i * 8 + lrow8;
      const unsigned short* src =
          QKV + kgbase + (size_t)(kt * 64 + key) * 2560 + (lbo >> 1);
      gload16(src, lds + w * 1024 + i * 512);
    }
  };
  auto stageV = [&](int kt) {
#pragma unroll
    for (int i = 0; i < 6; i++) {
      int vd = w * 48 + i * 8 + lrow8;
      const unsigned short* src =
          Vt + vgbase + (size_t)vd * 1536 + kt * 64 + (lbo >> 1);
      gload16(src, lds + 4096 + w * 3072 + i * 512);
    }
  };

  stageK(0);
  __syncthreads();

  for (int jt = 0; jt < 6; jt++) {
    // issue V(jt) DMA; drains at the MID barrier
    stageV(jt);

    const int j0g = kh * 384 + jt * 64;
    const int moff1 = j0g - (qp + 16) + 1520;  // rel-window base for qi=1

    // ---- content scores: each K fragment (from LDS) feeds BOTH q-tiles
    f32x4 Sc[2][4];
#pragma unroll
    for (int nt = 0; nt < 4; nt++) {
      const int kro = (nt * 16 + c) * 64;
      bf16x8 kf0 = *(const bf16x8*)(lds + kro + ((g * 8) ^ c7s));
      bf16x8 kf1 = *(const bf16x8*)(lds + kro + ((32 + g * 8) ^ c7s));
      f32x4 z0 = (f32x4){0.f, 0.f, 0.f, 0.f};
      z0 = __builtin_amdgcn_mfma_f32_16x16x32_bf16(aqw[0][0], kf0, z0, 0, 0, 0);
      z0 = __builtin_amdgcn_mfma_f32_16x16x32_bf16(aqw[0][1], kf1, z0, 0, 0, 0);
      Sc[0][nt] = z0;
      f32x4 z1 = (f32x4){0.f, 0.f, 0.f, 0.f};
      z1 = __builtin_amdgcn_mfma_f32_16x16x32_bf16(aqw[1][0], kf0, z1, 0, 0, 0);
      z1 = __builtin_amdgcn_mfma_f32_16x16x32_bf16(aqw[1][1], kf1, z1, 0, 0, 0);
      Sc[1][nt] = z1;
    }

    // ---- rel band: union pass over 6 rk tiles serves both windows (r4 code)
    float bandp0[4], bandp1[4];
    {  // j = 0: qi=1 initial only
      int mg = moff1 + c;
      const unsigned short* rrow = rkh + (size_t)mg * 512;
      f32x4 z = (f32x4){0.f, 0.f, 0.f, 0.f};
      z = __builtin_amdgcn_mfma_f32_16x16x32_bf16(aqr[1][0], *(const bf16x8*)(rrow + g * 8), z, 0, 0, 0);
      z = __builtin_amdgcn_mfma_f32_16x16x32_bf16(aqr[1][1], *(const bf16x8*)(rrow + 32 + g * 8), z, 0, 0, 0);
#pragma unroll
      for (int r = 0; r < 4; r++)
        bandp1[r] = __int_as_float(__builtin_amdgcn_ds_bpermute(baddr[r], __float_as_int(z[r])));
    }
#pragma unroll
    for (int j = 1; j <= 5; j++) {
      int mg = moff1 + 16 * j + c;
      if (mg > 3070) mg = 3070;  // clamped lane feeds only unused band slots
      const unsigned short* rrow = rkh + (size_t)mg * 512;
      bf16x8 rf0 = *(const bf16x8*)(rrow + g * 8);
      bf16x8 rf1 = *(const bf16x8*)(rrow + 32 + g * 8);
      {  // qi=0 uses this tile as window index j-1
        f32x4 z = (f32x4){0.f, 0.f, 0.f, 0.f};
        z = __builtin_amdgcn_mfma_f32_16x16x32_bf16(aqr[0][0], rf0, z, 0, 0, 0);
        z = __builtin_amdgcn_mfma_f32_16x16x32_bf16(aqr[0][1], rf1, z, 0, 0, 0);
        if (j == 1) {
#pragma unroll
          for (int r = 0; r < 4; r++)
            bandp0[r] = __int_as_float(__builtin_amdgcn_ds_bpermute(baddr[r], __float_as_int(z[r])));
        } else {
          const int nt = j - 2;
#pragma unroll
          for (int r = 0; r < 4; r++) {
            float bandc = __int_as_float(__builtin_amdgcn_ds_bpermute(baddr[r], __float_as_int(z[r])));
            Sc[0][nt][r] += bsel[r] ? bandc : bandp0[r];
            bandp0[r] = bandc;
          }
        }
      }
      if (j <= 4) {  // qi=1 uses this tile as window index j
        f32x4 z = (f32x4){0.f, 0.f, 0.f, 0.f};
        z = __builtin_amdgcn_mfma_f32_16x16x32_bf16(aqr[1][0], rf0, z, 0, 0, 0);
        z = __builtin_amdgcn_mfma_f32_16x16x32_bf16(aqr[1][1], rf1, z, 0, 0, 0);
        const int nt = j - 1;
#pragma unroll
        for (int r = 0; r < 4; r++) {
          float bandc = __int_as_float(__builtin_amdgcn_ds_bpermute(baddr[r], __float_as_int(z[r])));
          Sc[1][nt][r] += bsel[r] ? bandc : bandp1[r];
          bandp1[r] = bandc;
        }
      }
    }

    // ---- p = exp2(lg) (LOG2E pre-folded); partial sums; P -> swizzled slabs
#pragma unroll
    for (int qi = 0; qi < 2; qi++) {
      unsigned short* slab = lds + 16384 + (2 * w + qi) * 1024;
#pragma unroll
      for (int nt = 0; nt < 4; nt++)
#pragma unroll
        for (int r = 0; r < 4; r++) {
          float p = exp2f(Sc[qi][nt][r]);
          lrow[qi][r] += p;
          int q = g * 4 + r;
          slab[q * 64 + ((nt * 16 + c) ^ ((q & 7) << 3))] = f2b(p);
        }
    }

    __syncthreads();  // MID: P visible to all waves; V(jt) DMA drained

    // issue K(jt+1) DMA into the (now free) single K buffer; drains at END
    if (jt < 5) stageK(jt + 1);

    // ---- PV: staged V tile serves ALL 8 q-slabs (this wave's 48 vdims)
    bf16x8 vf0[3], vf1[3];
#pragma unroll
    for (int vt = 0; vt < 3; vt++) {
      const int vro = 4096 + (w * 48 + vt * 16 + c) * 64;
      vf0[vt] = *(const bf16x8*)(lds + vro + ((g * 8) ^ c7s));
      vf1[vt] = *(const bf16x8*)(lds + vro + ((32 + g * 8) ^ c7s));
    }
    __builtin_amdgcn_s_setprio(1);
#pragma unroll
    for (int s = 0; s < 8; s++) {
      const unsigned short* slab = lds + 16384 + s * 1024;
      bf16x8 ap0 = *(const bf16x8*)(slab + c * 64 + ((g * 8) ^ c7s));
      bf16x8 ap1 = *(const bf16x8*)(slab + c * 64 + ((32 + g * 8) ^ c7s));
#pragma unroll
      for (int vt = 0; vt < 3; vt++) {
        Ofr[s][vt] = __builtin_amdgcn_mfma_f32_16x16x32_bf16(ap0, vf0[vt], Ofr[s][vt], 0, 0, 0);
        Ofr[s][vt] = __builtin_amdgcn_mfma_f32_16x16x32_bf16(ap1, vf1[vt], Ofr[s][vt], 0, 0, 0);
      }
    }
    __builtin_amdgcn_s_setprio(0);

    __syncthreads();  // END: PV ds_reads done; K(jt+1) DMA drained
  }

  // ---- l partials: reduce lrow over the 16 c-lanes, write global (no merge)
#pragma unroll
  for (int qi = 0; qi < 2; qi++)
#pragma unroll
    for (int r = 0; r < 4; r++) {
      float s = lrow[qi][r];
      s += __shfl_xor(s, 1, 64);
      s += __shfl_xor(s, 2, 64);
      s += __shfl_xor(s, 4, 64);
      s += __shfl_xor(s, 8, 64);
      lrow[qi][r] = s;
    }
  if (c == 0) {
#pragma unroll
    for (int qi = 0; qi < 2; qi++)
#pragma unroll
      for (int r = 0; r < 4; r++)
        lpart[(size_t)((kh * 2 + b) * 8 + h) * 1536 + qp + qi * 16 + g * 4 + r] =
            lrow[qi][r];
  }
  // ---- O partials (unnormalized, bf16); waves own disjoint vdim ranges
#pragma unroll
  for (int s = 0; s < 8; s++)
#pragma unroll
    for (int vt = 0; vt < 3; vt++)
#pragma unroll
      for (int r = 0; r < 4; r++)
        Opart[(size_t)(kh * 3072 + b * 1536 + i0b + s * 16 + g * 4 + r) * 1536 +
              h * 192 + w * 48 + vt * 16 + c] = f2b(Ofr[s][vt][r]);
}

// ------------------------------------------------------- key-split finalize
// out_bf16[row][col] = (sum of 4 bf16 partials) / (sum of 4 l's); 8 cols/thr.
__global__ __launch_bounds__(256) void k_fin(
    const unsigned short* __restrict__ Op, const float* __restrict__ lp,
    unsigned short* __restrict__ O) {
  int idx = (blockIdx.x * 256 + threadIdx.x) * 8;
  int row = idx / 1536, c0 = idx % 1536;  // row in [0,3072)
  int b = row >= 1536;
  int q = row - b * 1536, hh = c0 / 192;
  float l = 0.f;
#pragma unroll
  for (int kh = 0; kh < 4; kh++)
    l += lp[(size_t)((kh * 2 + b) * 8 + hh) * 1536 + q];
  float sc = 1.f / l;
  float acc[8] = {0.f, 0.f, 0.f, 0.f, 0.f, 0.f, 0.f, 0.f};
#pragma unroll
  for (int kh = 0; kh < 4; kh++) {
    const ushort4* p = (const ushort4*)(Op + (size_t)(kh * 3072 + row) * 1536 + c0);
#pragma unroll
    for (int half = 0; half < 2; half++) {
      ushort4 a = p[half];
      acc[half * 4 + 0] += b2f(a.x);
      acc[half * 4 + 1] += b2f(a.y);
      acc[half * 4 + 2] += b2f(a.z);
      acc[half * 4 + 3] += b2f(a.w);
    }
  }
#pragma unroll
  for (int half = 0; half < 2; half++) {
    ushort4 o;
    o.x = f2b(acc[half * 4 + 0] * sc);
    o.y = f2b(acc[half * 4 + 1] * sc);
    o.z = f2b(acc[half * 4 + 2] * sc);
    o.w = f2b(acc[half * 4 + 3] * sc);
    *(ushort4*)(O + (size_t)row * 1536 + c0 + half * 4) = o;
  }
}

// ------------------------------------------------------------------ launcher
extern "C" void kernel_launch(void* const* d_in, const int* in_sizes, int n_in,
                              void* d_out, int out_size, void* d_ws, size_t ws_size,
                              hipStream_t stream) {
  const float* x    = (const float*)d_in[0];
  const float* Wq   = (const float*)d_in[1];
  const float* Wk   = (const float*)d_in[2];
  const float* Wv   = (const float*)d_in[3];
  const float* Wrk  = (const float*)d_in[4];
  const float* Wemb = (const float*)d_in[5];
  const float* rwb  = (const float*)d_in[6];
  const float* rrb  = (const float*)d_in[7];

  char* ws = (char*)d_ws;
  size_t off = 0;
  auto alloc = [&](size_t bytes) -> void* {
    void* p = ws + off;
    off += (bytes + 255) & ~(size_t)255;
    return p;
  };
  unsigned short* xb    = (unsigned short*)alloc((size_t)3072 * 1536 * 2);
  unsigned short* WqkvT = (unsigned short*)alloc((size_t)2560 * 1536 * 2);
  unsigned short* WembT = (unsigned short*)alloc((size_t)1536 * 1536 * 2);
  unsigned short* WrkT  = (unsigned short*)alloc((size_t)512 * 192 * 2);
  unsigned short* QKV   = (unsigned short*)alloc((size_t)3072 * 2560 * 2);
  unsigned short* Vt    = (unsigned short*)alloc((size_t)2 * 1536 * 1536 * 2);
  unsigned short* emb   = (unsigned short*)alloc((size_t)3072 * 192 * 2);
  unsigned short* rkb   = (unsigned short*)alloc((size_t)3072 * 512 * 2);
  unsigned short* Obuf  = (unsigned short*)alloc((size_t)3072 * 1536 * 2);
  unsigned short* Opart = (unsigned short*)alloc((size_t)4 * 3072 * 1536 * 2);
  float*          lpart = (float*)alloc((size_t)4 * 2 * 8 * 1536 * 4);

  // 1) fused prep: x->bf16, 5 weight transposes, positional emb (pmax const)
  k_prep<<<12000, 256, 0, stream>>>(x, Wq, Wk, Wv, Wemb, Wrk, xb, WqkvT, WembT, WrkT, emb);
  // 2) fused QKV projection
  k_gemm<<<dim3(20, 24), 256, 0, stream>>>(xb, WqkvT, QKV, nullptr, 3072, 2560, 1536);
  // 3) rel-key GEMM + V transposes
  k_mid<<<4704, 256, 0, stream>>>(emb, WrkT, rkb, QKV, Vt);
  // 4) flash attention (QBLK=128, key-split=4, 48KB LDS, launch_bounds(256,2))
  k_attn<<<768, 256, 0, stream>>>(QKV, rkb, Vt, rwb, rrb, Opart, lpart);
  // 5) merge key-split partials -> Obuf bf16
  k_fin<<<2304, 256, 0, stream>>>(Opart, lpart, Obuf);
  // 6) output projection -> f32 d_out
  k_gemm<<<dim3(12, 24), 256, 0, stream>>>(Obuf, WembT, nullptr, (float*)d_out, 3072, 1536, 1536);
}

// Round 9
// 258.175 us; speedup vs baseline: 1.3198x; 1.0799x over previous
//
#include <hip/hip_runtime.h>
#include <stdint.h>

#define DEVI __device__ __forceinline__
#define LOG2E 1.4426950408889634f

typedef short bf16x8 __attribute__((ext_vector_type(8)));
typedef float f32x4 __attribute__((ext_vector_type(4)));

// analytically-derived max of the gamma positional basis (i=0, ap=36):
// exp(3*ln36 - 3 - ln6 - 4*ln12) = 0.01867013 (input-independent constant)
#define PMAX 0.01867013f

DEVI float b2f(unsigned short u) {
  union { unsigned u32; float f; } x;
  x.u32 = ((unsigned)u) << 16;
  return x.f;
}
DEVI unsigned short f2b(float f) {
  union { float f32; unsigned u32; } x;
  x.f32 = f;
  unsigned u = x.u32;
  return (unsigned short)((u + 0x7FFFu + ((u >> 16) & 1u)) >> 16);
}

// async global->LDS, 16B per lane. LDS dest must be wave-uniform base + lane*16.
DEVI void gload16(const unsigned short* g, unsigned short* l) {
  __builtin_amdgcn_global_load_lds(
      (const __attribute__((address_space(1))) void*)g,
      (__attribute__((address_space(3))) void*)l, 16, 0, 0);
}

DEVI float gamma_prob(float ap, int i) {
  float mean = 48.f * (float)(i + 1);
  float conc = (mean / 24.f) * (mean / 24.f);
  float rate = mean / 576.f;
  if (ap == 0.f) return 1e-8f;
  float logp = (conc - 1.f) * logf(ap) - rate * ap - (lgammaf(conc) - conc * logf(rate));
  return expf(logp) + 1e-8f;
}

// ---------------------------------------------------- device transpose (32x32)
DEVI void dev_transpose(const float* srcf, const unsigned short* srcb, int src_ld,
                        unsigned short* dst, int dst_ld, int rows, int cols,
                        int bx, int by, unsigned short (*t)[33]) {
  int tx = threadIdx.x & 31, ty = threadIdx.x >> 5;
  int r0 = by * 32, c0 = bx * 32;
#pragma unroll
  for (int i = 0; i < 4; i++) {
    int r = r0 + ty + i * 8, cc = c0 + tx;
    if (r < rows && cc < cols)
      t[ty + i * 8][tx] = srcf ? f2b(srcf[(size_t)r * src_ld + cc])
                               : srcb[(size_t)r * src_ld + cc];
  }
  __syncthreads();
#pragma unroll
  for (int i = 0; i < 4; i++) {
    int dr = c0 + ty + i * 8, dc = r0 + tx;
    if (dr < cols && dc < rows) dst[(size_t)dr * dst_ld + dc] = t[tx][ty + i * 8];
  }
}

// ------------------------------------------------------------------ k_prep
__global__ __launch_bounds__(256) void k_prep(
    const float* __restrict__ x, const float* __restrict__ Wq,
    const float* __restrict__ Wk, const float* __restrict__ Wv,
    const float* __restrict__ Wemb, const float* __restrict__ Wrk,
    unsigned short* __restrict__ xb, unsigned short* __restrict__ WqkvT,
    unsigned short* __restrict__ WembT, unsigned short* __restrict__ WrkT,
    unsigned short* __restrict__ emb) {
  __shared__ unsigned short t[32][33];
  int bid = blockIdx.x;
  if (bid < 4608) {
    int i = (bid * 256 + threadIdx.x) * 4;
    float4 v = *(const float4*)(x + i);
    ushort4 o;
    o.x = f2b(v.x); o.y = f2b(v.y); o.z = f2b(v.z); o.w = f2b(v.w);
    *(ushort4*)(xb + i) = o;
  } else if (bid < 5376) {
    int s = bid - 4608;
    dev_transpose(Wq, nullptr, 512, WqkvT, 1536, 1536, 512, s % 16, s / 16, t);
  } else if (bid < 6144) {
    int s = bid - 5376;
    dev_transpose(Wk, nullptr, 512, WqkvT + (size_t)512 * 1536, 1536, 1536, 512, s % 16, s / 16, t);
  } else if (bid < 8448) {
    int s = bid - 6144;
    dev_transpose(Wv, nullptr, 1536, WqkvT + (size_t)1024 * 1536, 1536, 1536, 1536, s % 48, s / 48, t);
  } else if (bid < 10752) {
    int s = bid - 8448;
    dev_transpose(Wemb, nullptr, 1536, WembT, 1536, 1536, 1536, s % 48, s / 48, t);
  } else if (bid < 10848) {
    int s = bid - 10752;
    dev_transpose(Wrk, nullptr, 512, WrkT, 192, 192, 512, s % 16, s / 16, t);
  } else {
    int idx = (bid - 10848) * 256 + threadIdx.x;
    if (idx < 3071 * 96) {
      int m = idx / 96, cc = idx % 96;
      float ap = fabsf((float)(m - 1535));
      float val;
      if (cc < 32) {
        float max_range = logf(1536.f) * 1.4426950408889634f;
        float l = 3.f + (float)cc * (max_range - 3.f) / 31.f;
        val = exp2f(-ap * exp2f(-l));
      } else if (cc < 64) {
        float width = exp2f((float)(cc - 31)) - 1.f;
        val = (width > ap) ? 1.f : 0.f;
      } else {
        val = gamma_prob(ap, cc - 64) / PMAX;
      }
      float sgn = (m > 1535) ? 1.f : ((m < 1535) ? -1.f : 0.f);
      emb[(size_t)m * 192 + cc] = f2b(val);
      emb[(size_t)m * 192 + 96 + cc] = f2b(sgn * val);
    }
  }
}

// ---------------------------------------------------------------- MFMA GEMM
DEVI void dev_gemm(const unsigned short* __restrict__ A, const unsigned short* __restrict__ Bt,
                   unsigned short* Cb, float* Cf, int M, int N, int K,
                   int bx, int by, unsigned short* As, unsigned short* Bs) {
  int tid = threadIdx.x;
  int w = tid >> 6, L = tid & 63, g = L >> 4, c = L & 15;
  int m0 = by << 7, n0 = bx << 7;
  int wm = (w >> 1) << 6, wn = (w & 1) << 6;
  f32x4 acc[4][4];
#pragma unroll
  for (int i = 0; i < 4; i++)
#pragma unroll
    for (int j = 0; j < 4; j++) acc[i][j] = (f32x4){0.f, 0.f, 0.f, 0.f};
  int nkt = K >> 5;
  for (int kt = 0; kt < nkt; kt++) {
    int k0 = kt << 5;
#pragma unroll
    for (int i2 = 0; i2 < 2; i2++) {
      int cidx = tid + (i2 << 8);
      int row = cidx >> 2, kc = (cidx & 3) << 3;
      int ra = m0 + row;
      if (ra >= M) ra = M - 1;
      gload16(A + (size_t)ra * K + k0 + kc, As + cidx * 8);
      gload16(Bt + (size_t)(n0 + row) * K + k0 + kc, Bs + cidx * 8);
    }
    __syncthreads();
    bf16x8 af[4], bfr[4];
#pragma unroll
    for (int t = 0; t < 4; t++) af[t] = *(const bf16x8*)(As + (wm + t * 16 + c) * 32 + g * 8);
#pragma unroll
    for (int t = 0; t < 4; t++) bfr[t] = *(const bf16x8*)(Bs + (wn + t * 16 + c) * 32 + g * 8);
#pragma unroll
    for (int mt = 0; mt < 4; mt++)
#pragma unroll
      for (int nt = 0; nt < 4; nt++)
        acc[mt][nt] = __builtin_amdgcn_mfma_f32_16x16x32_bf16(af[mt], bfr[nt], acc[mt][nt], 0, 0, 0);
    __syncthreads();
  }
#pragma unroll
  for (int mt = 0; mt < 4; mt++)
#pragma unroll
    for (int nt = 0; nt < 4; nt++)
#pragma unroll
      for (int r = 0; r < 4; r++) {
        int rr = m0 + wm + mt * 16 + g * 4 + r;
        if (rr < M) {
          size_t o = (size_t)rr * N + n0 + wn + nt * 16 + c;
          if (Cf) Cf[o] = acc[mt][nt][r];
          else Cb[o] = f2b(acc[mt][nt][r]);
        }
      }
}

// ---- V projection with TRANSPOSED epilogue: writes Vt[b*1536+cc][token].
// acc[mt][nt][r=0..3] = 4 consecutive TOKENS at one vd column -> one aligned
// 8B ushort4 store per (mt,nt). Vt row index: (b*8+h)*192+vd == b*1536+cc.
// Deletes the k_mid transpose pass entirely (r8).
DEVI void dev_gemm_vt(const unsigned short* __restrict__ A, const unsigned short* __restrict__ Bt,
                      unsigned short* __restrict__ Vt, int M, int N, int K,
                      int bx, int by, unsigned short* As, unsigned short* Bs) {
  int tid = threadIdx.x;
  int w = tid >> 6, L = tid & 63, g = L >> 4, c = L & 15;
  int m0 = by << 7, n0 = bx << 7;
  int wm = (w >> 1) << 6, wn = (w & 1) << 6;
  f32x4 acc[4][4];
#pragma unroll
  for (int i = 0; i < 4; i++)
#pragma unroll
    for (int j = 0; j < 4; j++) acc[i][j] = (f32x4){0.f, 0.f, 0.f, 0.f};
  int nkt = K >> 5;
  for (int kt = 0; kt < nkt; kt++) {
    int k0 = kt << 5;
#pragma unroll
    for (int i2 = 0; i2 < 2; i2++) {
      int cidx = tid + (i2 << 8);
      int row = cidx >> 2, kc = (cidx & 3) << 3;
      gload16(A + (size_t)(m0 + row) * K + k0 + kc, As + cidx * 8);
      gload16(Bt + (size_t)(n0 + row) * K + k0 + kc, Bs + cidx * 8);
    }
    __syncthreads();
    bf16x8 af[4], bfr[4];
#pragma unroll
    for (int t = 0; t < 4; t++) af[t] = *(const bf16x8*)(As + (wm + t * 16 + c) * 32 + g * 8);
#pragma unroll
    for (int t = 0; t < 4; t++) bfr[t] = *(const bf16x8*)(Bs + (wn + t * 16 + c) * 32 + g * 8);
#pragma unroll
    for (int mt = 0; mt < 4; mt++)
#pragma unroll
      for (int nt = 0; nt < 4; nt++)
        acc[mt][nt] = __builtin_amdgcn_mfma_f32_16x16x32_bf16(af[mt], bfr[nt], acc[mt][nt], 0, 0, 0);
    __syncthreads();
  }
  // transposed epilogue: 128-row tiles never cross the batch boundary (1536%128==0)
#pragma unroll
  for (int mt = 0; mt < 4; mt++) {
    int rr = m0 + wm + mt * 16 + g * 4;  // token row of r=0 (multiple of 4)
    int bb = rr >= 1536;
    int tok = rr - bb * 1536;
#pragma unroll
    for (int nt = 0; nt < 4; nt++) {
      int cc = n0 + wn + nt * 16 + c;   // global vd column in [0,1536)
      ushort4 o;
      o.x = f2b(acc[mt][nt][0]);
      o.y = f2b(acc[mt][nt][1]);
      o.z = f2b(acc[mt][nt][2]);
      o.w = f2b(acc[mt][nt][3]);
      *(ushort4*)(Vt + (size_t)(bb * 1536 + cc) * 1536 + tok) = o;
    }
  }
}

__global__ __launch_bounds__(256) void k_gemm(
    const unsigned short* __restrict__ A, const unsigned short* __restrict__ Bt,
    unsigned short* Cb, float* Cf, int M, int N, int K) {
  __shared__ unsigned short sm[8192];
  dev_gemm(A, Bt, Cb, Cf, M, N, K, blockIdx.x, blockIdx.y, sm, sm + 4096);
}

// ------------------------------------------------------------------ k_proj
// One launch replacing {QKV GEMM + k_mid}: [0,288) V-GEMM (writes Vt directly,
// transposed epilogue); [288,480) QK-GEMM -> QKV[3072][1024]; [480,576) rel-key
// GEMM emb x WrkT^T -> rkb. All depend only on k_prep outputs.
__global__ __launch_bounds__(256) void k_proj(
    const unsigned short* __restrict__ xb, const unsigned short* __restrict__ WqkvT,
    unsigned short* __restrict__ QKV, unsigned short* __restrict__ Vt,
    const unsigned short* __restrict__ emb, const unsigned short* __restrict__ WrkT,
    unsigned short* __restrict__ rkb) {
  __shared__ unsigned short sm[8192];
  int bid = blockIdx.x;
  if (bid < 288) {
    dev_gemm_vt(xb, WqkvT + (size_t)1024 * 1536, Vt, 3072, 1536, 1536,
                bid % 12, bid / 12, sm, sm + 4096);
  } else if (bid < 480) {
    int s = bid - 288;
    dev_gemm(xb, WqkvT, QKV, nullptr, 3072, 1024, 1536, s % 8, s / 8, sm, sm + 4096);
  } else {
    int s = bid - 480;
    dev_gemm(emb, WrkT, rkb, nullptr, 3071, 512, 192, s & 3, s >> 2, sm, sm + 4096);
  }
}

// ------------------------------------------------------------ flash attention
// r8 resubmit (r8 bench = container infra failure, no kernel verdict; full
// bounds/stride audit found no fault candidate). Identical to r7's verified
// k_attn except QKV is now [3072][1024] (Q cols [0,512), K cols [512,1024);
// V lives only in Vt). Stride 2560->1024.
// Structure: QBLK=128, key-split=4 (grid 768 = 12qb x 4kh x 2b x 8h, bid&7=h
// XCD swizzle), 4 waves, LDS 48KB: K [0,4096) V [4096,16384) P [16384,24576).
// Score phase: 2-q-tile union-rel (r4-verified); PV: vdim-split, staged V
// serves all 8 P slabs. bf16 O-partials + lpart, merged by k_fin.
__global__ __launch_bounds__(256, 2) void k_attn(
    const unsigned short* __restrict__ QKV, const unsigned short* __restrict__ rk,
    const unsigned short* __restrict__ Vt, const float* __restrict__ rwb,
    const float* __restrict__ rrb, unsigned short* __restrict__ Opart,
    float* __restrict__ lpart) {
  __shared__ unsigned short lds[24576];
  const int tid = threadIdx.x;
  const int w = tid >> 6, L = tid & 63, g = L >> 4, c = L & 15;
  const int bid = blockIdx.x;
  const int h = bid & 7, b = (bid >> 3) & 1, kh = (bid >> 4) & 3;
  const int i0b = (bid >> 6) << 7;   // 128-row q-block base (12 q-blocks)
  const int qp = i0b + w * 32;       // this wave's 32-row q-pair base
  const int bh = b * 8 + h;
  const int c7s = (c & 7) << 3;      // u16-index swizzle term for reads

  const int lrow8 = L >> 3;                                // 0..7
  const int lbo = (((L & 7) * 16) ^ ((lrow8 & 7) << 4));   // swizzled byte in 128B row

  bf16x8 aqw[2][2], aqr[2][2];
#pragma unroll
  for (int qi = 0; qi < 2; qi++) {
    const unsigned short* qrow =
        QKV + (size_t)(b * 1536 + qp + qi * 16 + c) * 1024 + h * 64;
#pragma unroll
    for (int ks = 0; ks < 2; ks++) {
      union { bf16x8 v; unsigned short s[8]; } uw, ur;
#pragma unroll
      for (int j = 0; j < 8; j++) {
        int d = ks * 32 + g * 8 + j;
        float qv = b2f(qrow[d]) * 0.125f;
        uw.s[j] = f2b((qv + rwb[h * 64 + d]) * LOG2E);
        ur.s[j] = f2b((qv + rrb[h * 64 + d]) * LOG2E);
      }
      aqw[qi][ks] = uw.v;
      aqr[qi][ks] = ur.v;
    }
  }

  int baddr[4], bsel[4];
#pragma unroll
  for (int r = 0; r < 4; r++) {
    int u = c - (g * 4 + r) + 15;  // in [0,30]
    baddr[r] = (((g << 4) | (u & 15)) << 2);
    bsel[r] = (u >> 4) & 1;
  }

  f32x4 Ofr[8][3];
#pragma unroll
  for (int s = 0; s < 8; s++)
#pragma unroll
    for (int t = 0; t < 3; t++) Ofr[s][t] = (f32x4){0.f, 0.f, 0.f, 0.f};
  float lrow[2][4] = {{0.f, 0.f, 0.f, 0.f}, {0.f, 0.f, 0.f, 0.f}};

  const unsigned short* rkh = rk + h * 64;
  const size_t kgbase = (size_t)(b * 1536 + kh * 384) * 1024 + 512 + h * 64;
  const size_t vgbase = (size_t)(bh * 192) * 1536 + kh * 384;

  auto stageK = [&](int kt) {
#pragma unroll
    for (int i = 0; i < 2; i++) {
      int key = w * 16 + i * 8 + lrow8;
      const unsigned short* src =
          QKV + kgbase + (size_t)(kt * 64 + key) * 1024 + (lbo >> 1);
      gload16(src, lds + w * 1024 + i * 512);
    }
  };
  auto stageV = [&](int kt) {
#pragma unroll
    for (int i = 0; i < 6; i++) {
      int vd = w * 48 + i * 8 + lrow8;
      const unsigned short* src =
          Vt + vgbase + (size_t)vd * 1536 + kt * 64 + (lbo >> 1);
      gload16(src, lds + 4096 + w * 3072 + i * 512);
    }
  };

  stageK(0);
  __syncthreads();

  for (int jt = 0; jt < 6; jt++) {
    stageV(jt);

    const int j0g = kh * 384 + jt * 64;
    const int moff1 = j0g - (qp + 16) + 1520;

    // ---- content scores
    f32x4 Sc[2][4];
#pragma unroll
    for (int nt = 0; nt < 4; nt++) {
      const int kro = (nt * 16 + c) * 64;
      bf16x8 kf0 = *(const bf16x8*)(lds + kro + ((g * 8) ^ c7s));
      bf16x8 kf1 = *(const bf16x8*)(lds + kro + ((32 + g * 8) ^ c7s));
      f32x4 z0 = (f32x4){0.f, 0.f, 0.f, 0.f};
      z0 = __builtin_amdgcn_mfma_f32_16x16x32_bf16(aqw[0][0], kf0, z0, 0, 0, 0);
      z0 = __builtin_amdgcn_mfma_f32_16x16x32_bf16(aqw[0][1], kf1, z0, 0, 0, 0);
      Sc[0][nt] = z0;
      f32x4 z1 = (f32x4){0.f, 0.f, 0.f, 0.f};
      z1 = __builtin_amdgcn_mfma_f32_16x16x32_bf16(aqw[1][0], kf0, z1, 0, 0, 0);
      z1 = __builtin_amdgcn_mfma_f32_16x16x32_bf16(aqw[1][1], kf1, z1, 0, 0, 0);
      Sc[1][nt] = z1;
    }

    // ---- rel band: union pass over 6 rk tiles serves both windows
    float bandp0[4], bandp1[4];
    {
      int mg = moff1 + c;
      const unsigned short* rrow = rkh + (size_t)mg * 512;
      f32x4 z = (f32x4){0.f, 0.f, 0.f, 0.f};
      z = __builtin_amdgcn_mfma_f32_16x16x32_bf16(aqr[1][0], *(const bf16x8*)(rrow + g * 8), z, 0, 0, 0);
      z = __builtin_amdgcn_mfma_f32_16x16x32_bf16(aqr[1][1], *(const bf16x8*)(rrow + 32 + g * 8), z, 0, 0, 0);
#pragma unroll
      for (int r = 0; r < 4; r++)
        bandp1[r] = __int_as_float(__builtin_amdgcn_ds_bpermute(baddr[r], __float_as_int(z[r])));
    }
#pragma unroll
    for (int j = 1; j <= 5; j++) {
      int mg = moff1 + 16 * j + c;
      if (mg > 3070) mg = 3070;
      const unsigned short* rrow = rkh + (size_t)mg * 512;
      bf16x8 rf0 = *(const bf16x8*)(rrow + g * 8);
      bf16x8 rf1 = *(const bf16x8*)(rrow + 32 + g * 8);
      {
        f32x4 z = (f32x4){0.f, 0.f, 0.f, 0.f};
        z = __builtin_amdgcn_mfma_f32_16x16x32_bf16(aqr[0][0], rf0, z, 0, 0, 0);
        z = __builtin_amdgcn_mfma_f32_16x16x32_bf16(aqr[0][1], rf1, z, 0, 0, 0);
        if (j == 1) {
#pragma unroll
          for (int r = 0; r < 4; r++)
            bandp0[r] = __int_as_float(__builtin_amdgcn_ds_bpermute(baddr[r], __float_as_int(z[r])));
        } else {
          const int nt = j - 2;
#pragma unroll
          for (int r = 0; r < 4; r++) {
            float bandc = __int_as_float(__builtin_amdgcn_ds_bpermute(baddr[r], __float_as_int(z[r])));
            Sc[0][nt][r] += bsel[r] ? bandc : bandp0[r];
            bandp0[r] = bandc;
          }
        }
      }
      if (j <= 4) {
        f32x4 z = (f32x4){0.f, 0.f, 0.f, 0.f};
        z = __builtin_amdgcn_mfma_f32_16x16x32_bf16(aqr[1][0], rf0, z, 0, 0, 0);
        z = __builtin_amdgcn_mfma_f32_16x16x32_bf16(aqr[1][1], rf1, z, 0, 0, 0);
        const int nt = j - 1;
#pragma unroll
        for (int r = 0; r < 4; r++) {
          float bandc = __int_as_float(__builtin_amdgcn_ds_bpermute(baddr[r], __float_as_int(z[r])));
          Sc[1][nt][r] += bsel[r] ? bandc : bandp1[r];
          bandp1[r] = bandc;
        }
      }
    }

    // ---- p = exp2(lg); partial sums; P -> swizzled slabs
#pragma unroll
    for (int qi = 0; qi < 2; qi++) {
      unsigned short* slab = lds + 16384 + (2 * w + qi) * 1024;
#pragma unroll
      for (int nt = 0; nt < 4; nt++)
#pragma unroll
        for (int r = 0; r < 4; r++) {
          float p = exp2f(Sc[qi][nt][r]);
          lrow[qi][r] += p;
          int q = g * 4 + r;
          slab[q * 64 + ((nt * 16 + c) ^ ((q & 7) << 3))] = f2b(p);
        }
    }

    __syncthreads();  // MID: P visible; V(jt) DMA drained

    if (jt < 5) stageK(jt + 1);

    // ---- PV: staged V tile serves ALL 8 q-slabs (this wave's 48 vdims)
    bf16x8 vf0[3], vf1[3];
#pragma unroll
    for (int vt = 0; vt < 3; vt++) {
      const int vro = 4096 + (w * 48 + vt * 16 + c) * 64;
      vf0[vt] = *(const bf16x8*)(lds + vro + ((g * 8) ^ c7s));
      vf1[vt] = *(const bf16x8*)(lds + vro + ((32 + g * 8) ^ c7s));
    }
    __builtin_amdgcn_s_setprio(1);
#pragma unroll
    for (int s = 0; s < 8; s++) {
      const unsigned short* slab = lds + 16384 + s * 1024;
      bf16x8 ap0 = *(const bf16x8*)(slab + c * 64 + ((g * 8) ^ c7s));
      bf16x8 ap1 = *(const bf16x8*)(slab + c * 64 + ((32 + g * 8) ^ c7s));
#pragma unroll
      for (int vt = 0; vt < 3; vt++) {
        Ofr[s][vt] = __builtin_amdgcn_mfma_f32_16x16x32_bf16(ap0, vf0[vt], Ofr[s][vt], 0, 0, 0);
        Ofr[s][vt] = __builtin_amdgcn_mfma_f32_16x16x32_bf16(ap1, vf1[vt], Ofr[s][vt], 0, 0, 0);
      }
    }
    __builtin_amdgcn_s_setprio(0);

    __syncthreads();  // END: PV ds_reads done; K(jt+1) DMA drained
  }

  // ---- l partials
#pragma unroll
  for (int qi = 0; qi < 2; qi++)
#pragma unroll
    for (int r = 0; r < 4; r++) {
      float s = lrow[qi][r];
      s += __shfl_xor(s, 1, 64);
      s += __shfl_xor(s, 2, 64);
      s += __shfl_xor(s, 4, 64);
      s += __shfl_xor(s, 8, 64);
      lrow[qi][r] = s;
    }
  if (c == 0) {
#pragma unroll
    for (int qi = 0; qi < 2; qi++)
#pragma unroll
      for (int r = 0; r < 4; r++)
        lpart[(size_t)((kh * 2 + b) * 8 + h) * 1536 + qp + qi * 16 + g * 4 + r] =
            lrow[qi][r];
  }
  // ---- O partials (unnormalized, bf16)
#pragma unroll
  for (int s = 0; s < 8; s++)
#pragma unroll
    for (int vt = 0; vt < 3; vt++)
#pragma unroll
      for (int r = 0; r < 4; r++)
        Opart[(size_t)(kh * 3072 + b * 1536 + i0b + s * 16 + g * 4 + r) * 1536 +
              h * 192 + w * 48 + vt * 16 + c] = f2b(Ofr[s][vt][r]);
}

// ------------------------------------------------------- key-split finalize
__global__ __launch_bounds__(256) void k_fin(
    const unsigned short* __restrict__ Op, const float* __restrict__ lp,
    unsigned short* __restrict__ O) {
  int idx = (blockIdx.x * 256 + threadIdx.x) * 8;
  int row = idx / 1536, c0 = idx % 1536;  // row in [0,3072)
  int b = row >= 1536;
  int q = row - b * 1536, hh = c0 / 192;
  float l = 0.f;
#pragma unroll
  for (int kh = 0; kh < 4; kh++)
    l += lp[(size_t)((kh * 2 + b) * 8 + hh) * 1536 + q];
  float sc = 1.f / l;
  float acc[8] = {0.f, 0.f, 0.f, 0.f, 0.f, 0.f, 0.f, 0.f};
#pragma unroll
  for (int kh = 0; kh < 4; kh++) {
    const ushort4* p = (const ushort4*)(Op + (size_t)(kh * 3072 + row) * 1536 + c0);
#pragma unroll
    for (int half = 0; half < 2; half++) {
      ushort4 a = p[half];
      acc[half * 4 + 0] += b2f(a.x);
      acc[half * 4 + 1] += b2f(a.y);
      acc[half * 4 + 2] += b2f(a.z);
      acc[half * 4 + 3] += b2f(a.w);
    }
  }
#pragma unroll
  for (int half = 0; half < 2; half++) {
    ushort4 o;
    o.x = f2b(acc[half * 4 + 0] * sc);
    o.y = f2b(acc[half * 4 + 1] * sc);
    o.z = f2b(acc[half * 4 + 2] * sc);
    o.w = f2b(acc[half * 4 + 3] * sc);
    *(ushort4*)(O + (size_t)row * 1536 + c0 + half * 4) = o;
  }
}

// ------------------------------------------------------------------ launcher
extern "C" void kernel_launch(void* const* d_in, const int* in_sizes, int n_in,
                              void* d_out, int out_size, void* d_ws, size_t ws_size,
                              hipStream_t stream) {
  const float* x    = (const float*)d_in[0];
  const float* Wq   = (const float*)d_in[1];
  const float* Wk   = (const float*)d_in[2];
  const float* Wv   = (const float*)d_in[3];
  const float* Wrk  = (const float*)d_in[4];
  const float* Wemb = (const float*)d_in[5];
  const float* rwb  = (const float*)d_in[6];
  const float* rrb  = (const float*)d_in[7];

  char* ws = (char*)d_ws;
  size_t off = 0;
  auto alloc = [&](size_t bytes) -> void* {
    void* p = ws + off;
    off += (bytes + 255) & ~(size_t)255;
    return p;
  };
  unsigned short* xb    = (unsigned short*)alloc((size_t)3072 * 1536 * 2);
  unsigned short* WqkvT = (unsigned short*)alloc((size_t)2560 * 1536 * 2);
  unsigned short* WembT = (unsigned short*)alloc((size_t)1536 * 1536 * 2);
  unsigned short* WrkT  = (unsigned short*)alloc((size_t)512 * 192 * 2);
  unsigned short* QKV   = (unsigned short*)alloc((size_t)3072 * 1024 * 2);
  unsigned short* Vt    = (unsigned short*)alloc((size_t)2 * 1536 * 1536 * 2);
  unsigned short* emb   = (unsigned short*)alloc((size_t)3072 * 192 * 2);
  unsigned short* rkb   = (unsigned short*)alloc((size_t)3072 * 512 * 2);
  unsigned short* Obuf  = (unsigned short*)alloc((size_t)3072 * 1536 * 2);
  unsigned short* Opart = (unsigned short*)alloc((size_t)4 * 3072 * 1536 * 2);
  float*          lpart = (float*)alloc((size_t)4 * 2 * 8 * 1536 * 4);

  // 1) fused prep: x->bf16, 5 weight transposes, positional emb
  k_prep<<<12000, 256, 0, stream>>>(x, Wq, Wk, Wv, Wemb, Wrk, xb, WqkvT, WembT, WrkT, emb);
  // 2) fused projections: V (direct->Vt transposed) + QK + rel-key GEMM
  k_proj<<<576, 256, 0, stream>>>(xb, WqkvT, QKV, Vt, emb, WrkT, rkb);
  // 3) flash attention (QBLK=128, key-split=4, 48KB LDS)
  k_attn<<<768, 256, 0, stream>>>(QKV, rkb, Vt, rwb, rrb, Opart, lpart);
  // 4) merge key-split partials -> Obuf bf16
  k_fin<<<2304, 256, 0, stream>>>(Opart, lpart, Obuf);
  // 5) output projection -> f32 d_out
  k_gemm<<<dim3(12, 24), 256, 0, stream>>>(Obuf, WembT, nullptr, (float*)d_out, 3072, 1536, 1536);
}